// Round 8
// baseline (8243.860 us; speedup 1.0000x reference)
//
#include <hip/hip_runtime.h>

#define BATCH 128
#define SEQ   512
#define EMB   512
#define HID   1024
#define NCLS  1000
#define NBLK  128    // 8 row groups x 16 blocks
#define TPB   512    // 8 waves; split-K: wave w owns hi K-steps {w+8m}, lo {w+8mm}

using short8 = __attribute__((ext_vector_type(8))) short;
using f32x4  = __attribute__((ext_vector_type(4))) float;
typedef unsigned long long u64;

__device__ __forceinline__ short f2bf(float f) {
    unsigned u = __float_as_uint(f);
    unsigned r = (u + 0x7fffu + ((u >> 16) & 1u)) >> 16;   // RNE
    return (short)r;
}
__device__ __forceinline__ float bf2f(short s) {
    unsigned u = ((unsigned)(unsigned short)s) << 16;
    return __uint_as_float(u);
}
__device__ __forceinline__ short8 pack8(float4 a, float4 b) {
    short8 s;
    s[0] = f2bf(a.x); s[1] = f2bf(a.y); s[2] = f2bf(a.z); s[3] = f2bf(a.w);
    s[4] = f2bf(b.x); s[5] = f2bf(b.y); s[6] = f2bf(b.z); s[7] = f2bf(b.w);
    return s;
}

// ---- ws layout (bytes) ----
// Tagged exchange (R4's verified format), parity-doubled:
//   u64 = { (t+1)<<32 | hi16<<16 | lo16 }
//   frag off (u64) = rg*16384 + ks'*512 + plane*256 + lane*4 + (i&3), plane = i>>2
// Flags (R5's verified layout): 8 rg x 128 u32, monotonic step counters; flag=k
// published AFTER vmcnt(0) drain of h(k)'s data stores => flag>=t implies h(t)
// data visible at MALL. Zero-init == "h=0 at epoch 0" for both.
#define OFF_EX0 0u
#define OFF_EX1 1048576u
#define OFF_FLG 2097152u         // 4 KiB
#define OFF_H   2101248u
#define ZERO_I4 131328u          // first 2101248 bytes zeroed as int4

__global__ void mgu_init(int4* __restrict__ ws4) {
    unsigned i = blockIdx.x * blockDim.x + threadIdx.x;
    if (i < ZERO_I4) ws4[i] = make_int4(0, 0, 0, 0);
}

// ---------------- sequential scan: speculative tagged load, flag-poll fallback ----------------
// Block b: rows r0=(b>>4)*16, h-cols jb=(b&15)*64 (R5 decomposition). Wave w: K-slice
// hi ks in {w+8m} (m=0,1 emb / 2..5 h), lo le in {w+8mm}. Consumer: issue all 32
// tagged u64 loads speculatively at step top (overlap emb MFMAs); validate tags
// in-register (data self-validates: tag+payload share the 8B atom). Stale frag =>
// R5 flag-poll (4B/lane), then reload that frag once (flag>=t => drained => fresh).
// Producer: TrP pack -> 2 tagged agent stores -> vmcnt(0) -> lane0 flag store.
// Skew: publish of t+1 follows this block's consumption of ALL step-t frags
// (reduction barrier) => no producer reaches t+2 writes while t is read => parity-2 OK.
__global__ __launch_bounds__(TPB, 1) void mgu_scan(
    const int* __restrict__ x, const float* __restrict__ emb,
    const float* __restrict__ Wz, const float* __restrict__ bz,
    const float* __restrict__ Wh, const float* __restrict__ bh,
    u64* __restrict__ ex0, u64* __restrict__ ex1,
    unsigned* __restrict__ flags, float* __restrict__ h)
{
    __shared__ f32x4    Rbuf[2][8][8][64];   // parity-dbuf reduction: 128 KiB
    __shared__ unsigned TrP[8][16][8];       // [wave][row][col] hi<<16|lo (wave-local)

    const int tid  = threadIdx.x;
    const int w    = tid >> 6;               // wave 0..7 = K-slice
    const int lane = tid & 63;
    const int q    = lane >> 4;              // quad 0..3
    const int n    = lane & 15;              // MFMA col / A-row index
    const int blk  = blockIdx.x;
    const int r0   = (blk >> 4) << 4;        // row-group base
    const int jb   = (blk & 15) << 6;        // block h-col base (64 cols)
    const int j0   = jb + (w << 3);          // this wave's output cols j0..j0+7
    const int frg  = (blk >> 4) * 16384;     // rowgroup base in exchange (u64 units)
    const int ksw  = ((blk & 15) << 1) + (w >> 2);   // fragment this wave writes
    const int qw   = w & 3;                          // quadrant within that fragment
    unsigned* flbase = flags + ((blk >> 4) << 7);
    unsigned* flw  = flbase + (ksw << 2) + qw;                             // producer slot
    const unsigned* flp = flbase + (w << 2) + (((lane & 15) >> 2) << 5) + (lane & 3);  // poll set

    // ---- persistent B fragments: Bf[c*6+m] = W[32*(w+8m)+q*8+i][jb+8c+(n&7)] ----
    const float* Wg = (n < 8) ? Wz : Wh;
    short8 Bf[48];
#pragma unroll
    for (int c = 0; c < 8; ++c) {
#pragma unroll
        for (int m = 0; m < 6; ++m) {
            const float* wp = Wg + jb + (c << 3) + (n & 7);
            short8 f;
#pragma unroll
            for (int i = 0; i < 8; ++i)
                f[i] = f2bf(wp[(long)((w + 8 * m) * 32 + q * 8 + i) * HID]);
            Bf[c * 6 + m] = f;
        }
    }
    const float bzv = bz[j0 + (n & 7)];
    const float bhv = bh[j0 + (n & 7)];

    float hreg[4] = {0.f, 0.f, 0.f, 0.f};    // lanes n<8: h, rows r0+q*4+r2, col j0+n

    const int xrow = (r0 + n) * SEQ;         // token stream for A-row n
    const int eoff = (w << 5) + (q << 3);    // emb frag base (floats), +256*m

    // prefetch emb fragments for t=0
    short8 fe0, fe1;
    {
        int tok = x[xrow];
        const float* ep = emb + (long)tok * EMB + eoff;
        float4 a0 = *(const float4*)(ep);
        float4 a1 = *(const float4*)(ep + 4);
        float4 b0 = *(const float4*)(ep + 256);
        float4 b1 = *(const float4*)(ep + 260);
        fe0 = pack8(a0, a1);
        fe1 = pack8(b0, b1);
    }

    for (int t = 0; t < SEQ; ++t) {
        const u64* EXr = (t & 1) ? ex1 : ex0;
        u64*       EXw = (t & 1) ? ex0 : ex1;
        const unsigned want = (unsigned)t;

        // next token early (independent)
        int tok_nxt = x[xrow + ((t < SEQ - 1) ? t + 1 : t)];

        const u64* fb[4];
#pragma unroll
        for (int mm = 0; mm < 4; ++mm)
            fb[mm] = EXr + frg + (w + 8 * mm) * 512 + (lane << 2);

        // ---- speculative tagged loads: all 4 fragments, straight to regs ----
        u64 ev[32];
#pragma unroll
        for (int mm = 0; mm < 4; ++mm)
#pragma unroll
            for (int i = 0; i < 8; ++i)
                ev[mm * 8 + i] = __hip_atomic_load(fb[mm] + (i >> 2) * 256 + (i & 3),
                                    __ATOMIC_RELAXED, __HIP_MEMORY_SCOPE_AGENT);

        f32x4 acc[8];
#pragma unroll
        for (int c = 0; c < 8; ++c) acc[c] = (f32x4){0.f, 0.f, 0.f, 0.f};

        // ---- emb MFMAs overlap the in-flight speculative loads ----
#pragma unroll
        for (int c = 0; c < 8; ++c)
            acc[c] = __builtin_amdgcn_mfma_f32_16x16x32_bf16(fe0, Bf[c * 6 + 0], acc[c], 0, 0, 0);
#pragma unroll
        for (int c = 0; c < 8; ++c)
            acc[c] = __builtin_amdgcn_mfma_f32_16x16x32_bf16(fe1, Bf[c * 6 + 1], acc[c], 0, 0, 0);

        // ---- validate tags; on stale: flag-poll (cheap), reload stale frags once ----
        for (;;) {
            bool okf[4]; bool allok = true;
#pragma unroll
            for (int mm = 0; mm < 4; ++mm) {
                bool ok = true;
#pragma unroll
                for (int i = 0; i < 8; ++i)
                    ok = ok && ((unsigned)(ev[mm * 8 + i] >> 32) == want);
                okf[mm] = __all((int)ok);
                allok = allok && okf[mm];
            }
            if (allok) break;
            {   // R5's proven poll: flag >= t implies h(t) drained to MALL
                unsigned fv;
                do {
                    fv = __hip_atomic_load(flp, __ATOMIC_RELAXED, __HIP_MEMORY_SCOPE_AGENT);
                } while (!__all((int)(fv >= want)));
            }
#pragma unroll
            for (int mm = 0; mm < 4; ++mm) {
                if (!okf[mm]) {
#pragma unroll
                    for (int i = 0; i < 8; ++i)
                        ev[mm * 8 + i] = __hip_atomic_load(fb[mm] + (i >> 2) * 256 + (i & 3),
                                            __ATOMIC_RELAXED, __HIP_MEMORY_SCOPE_AGENT);
                }
            }
        }

        // ---- unpack + h MFMAs: per-frag hi then lo (R4's verified order) ----
#pragma unroll
        for (int mm = 0; mm < 4; ++mm) {
            short8 fh, fl;
#pragma unroll
            for (int i = 0; i < 8; ++i) {
                unsigned lo32 = (unsigned)ev[mm * 8 + i];
                fh[i] = (short)(unsigned short)(lo32 >> 16);
                fl[i] = (short)(unsigned short)(lo32 & 0xffffu);
            }
#pragma unroll
            for (int c = 0; c < 8; ++c)
                acc[c] = __builtin_amdgcn_mfma_f32_16x16x32_bf16(fh, Bf[c * 6 + 2 + mm], acc[c], 0, 0, 0);
#pragma unroll
            for (int c = 0; c < 8; ++c)
                acc[c] = __builtin_amdgcn_mfma_f32_16x16x32_bf16(fl, Bf[c * 6 + 2 + mm], acc[c], 0, 0, 0);
        }

        // ---- cross-wave reduction (parity-dbuf, one barrier per step) ----
#pragma unroll
        for (int c = 0; c < 8; ++c) Rbuf[t & 1][w][c][lane] = acc[c];
        __syncthreads();
        f32x4 r = Rbuf[t & 1][0][w][lane];
#pragma unroll
        for (int w2 = 1; w2 < 8; ++w2) r += Rbuf[t & 1][w2][w][lane];

        // z-pre in lanes n<8, h~-pre in n>=8 (same col); partner = lane^8
        float oarr[4];
        oarr[0] = __shfl_xor(r[0], 8, 64);
        oarr[1] = __shfl_xor(r[1], 8, 64);
        oarr[2] = __shfl_xor(r[2], 8, 64);
        oarr[3] = __shfl_xor(r[3], 8, 64);

        if (n < 8) {
            const int j = j0 + n;
#pragma unroll
            for (int r2 = 0; r2 < 4; ++r2) {
                float z  = 1.f / (1.f + __expf(-(r[r2] + bzv)));
                float ht = tanhf(oarr[r2] + bhv);
                float ho = hreg[r2];
                float hn = ho + z * (ht - ho);
                hreg[r2] = hn;
                if (t < SEQ - 1) {
                    short hi = f2bf(hn);
                    short lo = f2bf(hn - bf2f(hi));
                    TrP[w][q * 4 + r2][n] =
                        ((unsigned)(unsigned short)hi << 16) | (unsigned short)lo;
                } else {
                    h[(r0 + q * 4 + r2) * HID + j] = hn;   // final state
                }
            }
        }

        if (t < SEQ - 1) {
            // ---- publish: tagged data stores -> drain -> flag (R4 data + R5 ordering) ----
            const u64 tagw = ((u64)(unsigned)(t + 1)) << 32;
            const int off  = frg + ksw * 512 + qw * 64 + lane;
            unsigned h0 = TrP[w][lane >> 2][(lane & 3)];
            unsigned h1 = TrP[w][lane >> 2][4 + (lane & 3)];
            __hip_atomic_store(EXw + off,       tagw | h0, __ATOMIC_RELAXED, __HIP_MEMORY_SCOPE_AGENT);
            __hip_atomic_store(EXw + off + 256, tagw | h1, __ATOMIC_RELAXED, __HIP_MEMORY_SCOPE_AGENT);
            asm volatile("s_waitcnt vmcnt(0)" ::: "memory");   // data acked at LLC
            if (lane == 0)
                __hip_atomic_store(flw, (unsigned)(t + 1),
                                   __ATOMIC_RELAXED, __HIP_MEMORY_SCOPE_AGENT);
            // prefetch next emb fragments (overlaps peers' validation)
            const float* ep = emb + (long)tok_nxt * EMB + eoff;
            float4 a0 = *(const float4*)(ep);
            float4 a1 = *(const float4*)(ep + 4);
            float4 b0 = *(const float4*)(ep + 256);
            float4 b1 = *(const float4*)(ep + 260);
            fe0 = pack8(a0, a1);
            fe1 = pack8(b0, b1);
        }
    }
}

// ---------------- final FC: logits = h @ Wfc + bfc, full fp32 ----------------
__global__ __launch_bounds__(256) void mgu_fc(const float* __restrict__ h,
                                              const float* __restrict__ Wfc,
                                              const float* __restrict__ bfc,
                                              float* __restrict__ out) {
    __shared__ float hs[BATCH][65];
    const int tid = threadIdx.x;
    const int n0  = blockIdx.x * 8;
    const int b   = tid & 127;
    const int nn  = tid >> 7;
    const int nc  = n0 + nn * 4;
    float acc0 = 0.f, acc1 = 0.f, acc2 = 0.f, acc3 = 0.f;

    for (int k0 = 0; k0 < HID; k0 += 64) {
        __syncthreads();
#pragma unroll
        for (int jj = 0; jj < 8; ++jj) {
            int idx = tid + jj * 256;
            int bb  = idx >> 4;
            int kk  = (idx & 15) << 2;
            const float4 v = *(const float4*)(h + bb * HID + k0 + kk);
            hs[bb][kk] = v.x; hs[bb][kk + 1] = v.y; hs[bb][kk + 2] = v.z; hs[bb][kk + 3] = v.w;
        }
        __syncthreads();
#pragma unroll 8
        for (int k = 0; k < 64; ++k) {
            float hv = hs[b][k];
            const float4 wv = *(const float4*)(Wfc + (long)(k0 + k) * NCLS + nc);
            acc0 += hv * wv.x; acc1 += hv * wv.y; acc2 += hv * wv.z; acc3 += hv * wv.w;
        }
    }
    float* op = out + b * NCLS + nc;
    op[0] = acc0 + bfc[nc + 0];
    op[1] = acc1 + bfc[nc + 1];
    op[2] = acc2 + bfc[nc + 2];
    op[3] = acc3 + bfc[nc + 3];
}

extern "C" void kernel_launch(void* const* d_in, const int* in_sizes, int n_in,
                              void* d_out, int out_size, void* d_ws, size_t ws_size,
                              hipStream_t stream) {
    const int*   x   = (const int*)  d_in[0];
    const float* emb = (const float*)d_in[1];
    const float* Wz  = (const float*)d_in[2];
    const float* bz  = (const float*)d_in[3];
    const float* Wh  = (const float*)d_in[4];
    const float* bh  = (const float*)d_in[5];
    const float* Wfc = (const float*)d_in[6];
    const float* bfc = (const float*)d_in[7];
    float* out = (float*)d_out;

    char* ws = (char*)d_ws;
    u64*      ex0   = (u64*)     (ws + OFF_EX0);
    u64*      ex1   = (u64*)     (ws + OFF_EX1);
    unsigned* flags = (unsigned*)(ws + OFF_FLG);
    float*    h     = (float*)   (ws + OFF_H);

    mgu_init<<<514, 256, 0, stream>>>((int4*)ws);   // zero exchange parities + flags

    mgu_scan<<<NBLK, TPB, 0, stream>>>(x, emb, Wz, bz, Wh, bh, ex0, ex1, flags, h);

    mgu_fc<<<125, 256, 0, stream>>>(h, Wfc, bfc, out);
}

// Round 9
// 3534.601 us; speedup vs baseline: 2.3323x; 2.3323x over previous
//
#include <hip/hip_runtime.h>

#define BATCH 128
#define SEQ   512
#define EMB   512
#define HID   1024
#define KC    1536   // EMB + HID
#define NCLS  1000
#define NBLK  128    // 8 row groups x 16 blocks
#define TPB   512    // 8 waves = 8 col groups per block

using short8 = __attribute__((ext_vector_type(8))) short;
using f32x4  = __attribute__((ext_vector_type(4))) float;
typedef unsigned long long u64;

__device__ __forceinline__ short f2bf(float f) {
    unsigned u = __float_as_uint(f);
    unsigned r = (u + 0x7fffu + ((u >> 16) & 1u)) >> 16;   // RNE
    return (short)r;
}
__device__ __forceinline__ float bf2f(short s) {
    unsigned u = ((unsigned)(unsigned short)s) << 16;
    return __uint_as_float(u);
}

// ---- ws layout (bytes) ----
// ch0/cl0 are the t=0 read buffers (must be zero); bars follow; then ch1/cl1/h.
#define OFF_CH0 0u
#define OFF_CL0 262144u
#define OFF_BAR 524288u          // 8 counters, 256B apart
#define OFF_CH1 526336u
#define OFF_CL1 788480u
#define OFF_H   1050624u
#define ZERO_I4 32896u           // first 526336 bytes zeroed as int4

__global__ void mgu_init(int4* __restrict__ ws4) {
    unsigned i = blockIdx.x * blockDim.x + threadIdx.x;
    if (i < ZERO_I4) ws4[i] = make_int4(0, 0, 0, 0);
}

// ---------------- sequential scan ----------------
// 128 blocks x 512 threads. Block b: row group r0 = (b>>4)*16 (16 batch rows),
// wave w covers gate-cols j0 = ((b&15)*8+w)*8 .. +7 (z in lanes n<8, h~ in n>=8).
// Weights resident in VGPRs (48 x short8 = 192 VGPRs/lane). h state in registers.
// Cross-block exchange: bf16 hi+lo h arrays via relaxed AGENT-scope atomics
// (bypass non-coherent L1/L2, coherence point = LLC) -> NO fences, NO L2 writeback.
// Row groups are fully independent: 8 separate 16-block barriers.
// [session note, R1-R8]: LDS-broadcast staging, bank conflicts, exchange
// coalescing, RMW serialization and speculative/tagged transports were each
// isolated and tested; all tie or regress. The per-step cost is dominated by a
// protocol-invariant agent-scope visibility latency (~13-14k cy/step), so this
// structure is the measured optimum for this decomposition.
__global__ __launch_bounds__(TPB, 1) void mgu_scan(
    const int* __restrict__ x, const float* __restrict__ emb,
    const float* __restrict__ Wz, const float* __restrict__ bz,
    const float* __restrict__ Wh, const float* __restrict__ bh,
    short* __restrict__ ch0, short* __restrict__ cl0,
    short* __restrict__ ch1, short* __restrict__ cl1,
    unsigned* __restrict__ bars, float* __restrict__ h)
{
    __shared__ short As[16][1544];   // [row][k]: k<512 emb bf16, k>=512 h hi (pad->2-way free)
    __shared__ short Al[16][1032];   // [row][hcol]: h lo correction

    const int tid  = threadIdx.x;
    const int w    = tid >> 6;               // wave 0..7
    const int lane = tid & 63;
    const int q    = lane >> 4;              // quad 0..3
    const int n    = lane & 15;              // MFMA col / A-row index
    const int blk  = blockIdx.x;
    const int r0   = (blk >> 4) << 4;        // row-group base
    const int j0   = (((blk & 15) << 3) + w) << 3;
    unsigned* bar  = bars + ((blk >> 4) << 6);   // 256B-spaced counter per row group

    // ---- persistent weight fragments (B-frag: B[k=q*8+i][col=lane&15]) ----
    const float* Wg = (n < 8) ? Wz : Wh;
    const float* wp = Wg + j0 + (n & 7);
    short8 Bf[48];
#pragma unroll
    for (int ks = 0; ks < 48; ++ks) {
        short8 f;
#pragma unroll
        for (int i = 0; i < 8; ++i)
            f[i] = f2bf(wp[(long)(ks * 32 + q * 8 + i) * HID]);
        Bf[ks] = f;
    }
    const float bzv = bz[j0 + (n & 7)];
    const float bhv = bh[j0 + (n & 7)];

    float hreg[4] = {0.f, 0.f, 0.f, 0.f};    // lanes n<8: h state, rows r0+q*4+r2, col j0+n

    const int hrow = tid >> 5;               // emb staging: 16 rows x 32 threads
    const int hc0  = (tid & 31) << 4;        // 16 cols per thread

    auto stage_emb = [&](int tt) {           // gather emb[x[row,tt]] -> As[:,0:512] (cached loads ok: read-only)
        int tok = x[(r0 + hrow) * SEQ + tt];
        const float4* ep = (const float4*)(emb + (long)tok * EMB + hc0);
        float4 e0 = ep[0], e1 = ep[1], e2 = ep[2], e3 = ep[3];
        short8 s0, s1;
        s0[0] = f2bf(e0.x); s0[1] = f2bf(e0.y); s0[2] = f2bf(e0.z); s0[3] = f2bf(e0.w);
        s0[4] = f2bf(e1.x); s0[5] = f2bf(e1.y); s0[6] = f2bf(e1.z); s0[7] = f2bf(e1.w);
        s1[0] = f2bf(e2.x); s1[1] = f2bf(e2.y); s1[2] = f2bf(e2.z); s1[3] = f2bf(e2.w);
        s1[4] = f2bf(e3.x); s1[5] = f2bf(e3.y); s1[6] = f2bf(e3.z); s1[7] = f2bf(e3.w);
        *(short8*)&As[hrow][hc0]     = s0;
        *(short8*)&As[hrow][hc0 + 8] = s1;
    };

    stage_emb(0);

    for (int t = 0; t < SEQ; ++t) {
        const short* chR = (t & 1) ? ch1 : ch0;
        const short* clR = (t & 1) ? cl1 : cl0;
        short*       chW = (t & 1) ? ch0 : ch1;
        short*       clW = (t & 1) ? cl0 : cl1;

        // ---- stage h hi/lo -> LDS (coherent agent loads, 8B each; 16/thread) ----
        u64 hv[8], lv[8];
#pragma unroll
        for (int k2 = 0; k2 < 8; ++k2) {
            int idx = tid + (k2 << 9);
            int row = idx >> 8;
            int wc  = idx & 255;
            const u64* hp8 = (const u64*)(chR + (r0 + row) * HID);
            const u64* lp8 = (const u64*)(clR + (r0 + row) * HID);
            hv[k2] = __hip_atomic_load(hp8 + wc, __ATOMIC_RELAXED, __HIP_MEMORY_SCOPE_AGENT);
            lv[k2] = __hip_atomic_load(lp8 + wc, __ATOMIC_RELAXED, __HIP_MEMORY_SCOPE_AGENT);
        }
#pragma unroll
        for (int k2 = 0; k2 < 8; ++k2) {
            int idx = tid + (k2 << 9);
            int row = idx >> 8;
            int wc  = idx & 255;
            *(u64*)&As[row][512 + (wc << 2)] = hv[k2];
            *(u64*)&Al[row][wc << 2]         = lv[k2];
        }
        __syncthreads();

        // ---- MFMA: A from LDS, B resident ----
        const short* ap  = &As[n][q * 8];
        const short* alp = &Al[n][q * 8];
        f32x4 a0 = {0.f,0.f,0.f,0.f}, a1 = a0, a2 = a0, a3 = a0;
#pragma unroll
        for (int ks = 0; ks < 48; ks += 4) {
            short8 f0 = *(const short8*)(ap + (ks + 0) * 32);
            short8 f1 = *(const short8*)(ap + (ks + 1) * 32);
            short8 f2 = *(const short8*)(ap + (ks + 2) * 32);
            short8 f3 = *(const short8*)(ap + (ks + 3) * 32);
            a0 = __builtin_amdgcn_mfma_f32_16x16x32_bf16(f0, Bf[ks + 0], a0, 0, 0, 0);
            a1 = __builtin_amdgcn_mfma_f32_16x16x32_bf16(f1, Bf[ks + 1], a1, 0, 0, 0);
            a2 = __builtin_amdgcn_mfma_f32_16x16x32_bf16(f2, Bf[ks + 2], a2, 0, 0, 0);
            a3 = __builtin_amdgcn_mfma_f32_16x16x32_bf16(f3, Bf[ks + 3], a3, 0, 0, 0);
        }
#pragma unroll
        for (int e = 0; e < 32; e += 4) {    // lo correction reuses Bf[16..47]
            short8 g0 = *(const short8*)(alp + (e + 0) * 32);
            short8 g1 = *(const short8*)(alp + (e + 1) * 32);
            short8 g2 = *(const short8*)(alp + (e + 2) * 32);
            short8 g3 = *(const short8*)(alp + (e + 3) * 32);
            a0 = __builtin_amdgcn_mfma_f32_16x16x32_bf16(g0, Bf[16 + e + 0], a0, 0, 0, 0);
            a1 = __builtin_amdgcn_mfma_f32_16x16x32_bf16(g1, Bf[16 + e + 1], a1, 0, 0, 0);
            a2 = __builtin_amdgcn_mfma_f32_16x16x32_bf16(g2, Bf[16 + e + 2], a2, 0, 0, 0);
            a3 = __builtin_amdgcn_mfma_f32_16x16x32_bf16(g3, Bf[16 + e + 3], a3, 0, 0, 0);
        }
        f32x4 acc = (a0 + a1) + (a2 + a3);

        // z-pre in lanes n<8, h~-pre in lanes n>=8 (same col); partner = lane^8
        float o0 = __shfl_xor(acc[0], 8, 64);
        float o1 = __shfl_xor(acc[1], 8, 64);
        float o2 = __shfl_xor(acc[2], 8, 64);
        float o3 = __shfl_xor(acc[3], 8, 64);

        if (n < 8) {
            float zp[4] = {acc[0], acc[1], acc[2], acc[3]};
            float tp[4] = {o0, o1, o2, o3};
            const int j = j0 + n;
#pragma unroll
            for (int r2 = 0; r2 < 4; ++r2) {
                float z  = 1.f / (1.f + __expf(-(zp[r2] + bzv)));
                float ht = tanhf(tp[r2] + bhv);
                float ho = hreg[r2];
                float hn = ho + z * (ht - ho);
                hreg[r2] = hn;
                int rr = (r0 + q * 4 + r2) * HID + j;
                if (t < SEQ - 1) {
                    short hi = f2bf(hn);
                    __hip_atomic_store(chW + rr, hi, __ATOMIC_RELAXED, __HIP_MEMORY_SCOPE_AGENT);
                    __hip_atomic_store(clW + rr, f2bf(hn - bf2f(hi)), __ATOMIC_RELAXED, __HIP_MEMORY_SCOPE_AGENT);
                } else {
                    h[rr] = hn;          // final state, normal store (kernel-boundary flush)
                }
            }
        }

        if (t < SEQ - 1) {
            // release: __syncthreads drains vmcnt(0) (bypass stores complete => visible at LLC)
            __syncthreads();
            if (tid == 0)
                __hip_atomic_fetch_add(bar, 1u, __ATOMIC_RELAXED, __HIP_MEMORY_SCOPE_AGENT);
            stage_emb(t + 1);            // overlap emb gather with barrier wait
            if (tid == 0) {
                unsigned tgt = (unsigned)(t + 1) * 16u;
                while (__hip_atomic_load(bar, __ATOMIC_RELAXED, __HIP_MEMORY_SCOPE_AGENT) < tgt)
                    __builtin_amdgcn_s_sleep(1);
            }
            __syncthreads();
        }
    }
}

// ---------------- final FC: logits = h @ Wfc + bfc, full fp32 ----------------
__global__ __launch_bounds__(256) void mgu_fc(const float* __restrict__ h,
                                              const float* __restrict__ Wfc,
                                              const float* __restrict__ bfc,
                                              float* __restrict__ out) {
    __shared__ float hs[BATCH][65];
    const int tid = threadIdx.x;
    const int n0  = blockIdx.x * 8;
    const int b   = tid & 127;
    const int nn  = tid >> 7;
    const int nc  = n0 + nn * 4;
    float acc0 = 0.f, acc1 = 0.f, acc2 = 0.f, acc3 = 0.f;

    for (int k0 = 0; k0 < HID; k0 += 64) {
        __syncthreads();
#pragma unroll
        for (int jj = 0; jj < 8; ++jj) {
            int idx = tid + jj * 256;
            int bb  = idx >> 4;
            int kk  = (idx & 15) << 2;
            const float4 v = *(const float4*)(h + bb * HID + k0 + kk);
            hs[bb][kk] = v.x; hs[bb][kk + 1] = v.y; hs[bb][kk + 2] = v.z; hs[bb][kk + 3] = v.w;
        }
        __syncthreads();
#pragma unroll 8
        for (int k = 0; k < 64; ++k) {
            float hv = hs[b][k];
            const float4 wv = *(const float4*)(Wfc + (long)(k0 + k) * NCLS + nc);
            acc0 += hv * wv.x; acc1 += hv * wv.y; acc2 += hv * wv.z; acc3 += hv * wv.w;
        }
    }
    float* op = out + b * NCLS + nc;
    op[0] = acc0 + bfc[nc + 0];
    op[1] = acc1 + bfc[nc + 1];
    op[2] = acc2 + bfc[nc + 2];
    op[3] = acc3 + bfc[nc + 3];
}

extern "C" void kernel_launch(void* const* d_in, const int* in_sizes, int n_in,
                              void* d_out, int out_size, void* d_ws, size_t ws_size,
                              hipStream_t stream) {
    const int*   x   = (const int*)  d_in[0];
    const float* emb = (const float*)d_in[1];
    const float* Wz  = (const float*)d_in[2];
    const float* bz  = (const float*)d_in[3];
    const float* Wh  = (const float*)d_in[4];
    const float* bh  = (const float*)d_in[5];
    const float* Wfc = (const float*)d_in[6];
    const float* bfc = (const float*)d_in[7];
    float* out = (float*)d_out;

    char* ws = (char*)d_ws;
    short*    ch0  = (short*)   (ws + OFF_CH0);
    short*    cl0  = (short*)   (ws + OFF_CL0);
    unsigned* bars = (unsigned*)(ws + OFF_BAR);
    short*    ch1  = (short*)   (ws + OFF_CH1);
    short*    cl1  = (short*)   (ws + OFF_CL1);
    float*    h    = (float*)   (ws + OFF_H);

    mgu_init<<<129, 256, 0, stream>>>((int4*)ws);   // zero ch0/cl0/bars

    mgu_scan<<<NBLK, TPB, 0, stream>>>(x, emb, Wz, bz, Wh, bh,
                                       ch0, cl0, ch1, cl1, bars, h);

    mgu_fc<<<125, 256, 0, stream>>>(h, Wfc, bfc, out);
}